// Round 2
// baseline (399.418 us; speedup 1.0000x reference)
//
#include <hip/hip_runtime.h>

typedef __attribute__((ext_vector_type(4))) int int4v;
typedef __attribute__((ext_vector_type(16))) int int16v;

// ---------------------------------------------------------------------------
// Kernel 0: pack int32 weights (harness passes ALL integer inputs as int32)
// into contiguous int8. w32: [N*K] int32 in [-127,127] -> w8: [N*K] int8.
// ---------------------------------------------------------------------------
__global__ __launch_bounds__(256) void pack_w_kernel(const int* __restrict__ w32,
                                                     int* __restrict__ w8,
                                                     long n4) {
    long i = (long)blockIdx.x * 256 + threadIdx.x;  // one per 4 ints
    if (i >= n4) return;
    int4v v = ((const int4v*)w32)[i];
    w8[i] = (v[0] & 0xFF) | ((v[1] & 0xFF) << 8) |
            ((v[2] & 0xFF) << 16) | ((v[3] & 0xFF) << 24);
}

// ---------------------------------------------------------------------------
// Kernel 1: dynamic per-token symmetric int8 quantization (unchanged).
// ---------------------------------------------------------------------------
template <int NCHUNK>
__global__ __launch_bounds__(256) void quant_kernel(const float* __restrict__ x,
                                                    signed char* __restrict__ xq,
                                                    float* __restrict__ xs,
                                                    int K) {
    const int t = blockIdx.x;
    const int tid = threadIdx.x;
    const float4* row = (const float4*)(x + (size_t)t * K);

    float4 v[NCHUNK];
    float amax = 0.0f;
    #pragma unroll
    for (int i = 0; i < NCHUNK; ++i) {
        float4 f = row[i * 256 + tid];
        v[i] = f;
        amax = fmaxf(amax, fmaxf(fmaxf(fabsf(f.x), fabsf(f.y)),
                                 fmaxf(fabsf(f.z), fabsf(f.w))));
    }
    #pragma unroll
    for (int off = 32; off >= 1; off >>= 1)
        amax = fmaxf(amax, __shfl_xor(amax, off, 64));
    __shared__ float red[4];
    if ((tid & 63) == 0) red[tid >> 6] = amax;
    __syncthreads();
    amax = fmaxf(fmaxf(red[0], red[1]), fmaxf(red[2], red[3]));

    const float scale = fmaxf(amax, 1e-8f) / 127.0f;
    if (tid == 0) xs[t] = scale;
    const float inv = 1.0f / scale;

    int* orow = (int*)(xq + (size_t)t * K);
    #pragma unroll
    for (int i = 0; i < NCHUNK; ++i) {
        float4 f = v[i];
        int q0 = (int)fminf(fmaxf(rintf(f.x * inv), -128.0f), 127.0f);
        int q1 = (int)fminf(fmaxf(rintf(f.y * inv), -128.0f), 127.0f);
        int q2 = (int)fminf(fmaxf(rintf(f.z * inv), -128.0f), 127.0f);
        int q3 = (int)fminf(fmaxf(rintf(f.w * inv), -128.0f), 127.0f);
        orow[i * 256 + tid] =
            (q0 & 0xFF) | ((q1 & 0xFF) << 8) | ((q2 & 0xFF) << 16) | ((q3 & 0xFF) << 24);
    }
}

// ---------------------------------------------------------------------------
// Kernel 2: int8 GEMM, 256x256 8-phase schedule (T2+T3/T4+T5), now on
// v_mfma_i32_32x32x32_i8 (4404 TOPS ubench ceiling vs 3944 for 16x16x64;
// half the MFMA instruction count per phase).
//
// A: [M,K] i8 (x_q), B: [N,K] i8 (packed weight_q), C: [M,N] f32.
// 512 threads = 8 waves (2M x 4N); per-wave output 128x64 = 4x2 frags of
// 32x32; per K-tile (128 i8 = 4 k-steps of K=32) = 32 MFMA/wave split into
// 4 phases of 8. LDS = 2 dbuf x (A 256x128 + B 256x128) = 128 KiB.
//
// Swizzle (rule 21): global_load_lds dest linear; per-lane global SOURCE
// 16B-chunk pre-XORed with (row&7); fragment ds_read_b128 applies the same
// XOR. New read pattern chunk=((2ks+kb)^(lane&7)): 8 chunk values x 8 lanes
// = 2 lanes/bank = conflict-free (m136); R1 measured 0 conflicts with the
// equivalent 16x16 pattern.
//
// Fragment layout 32x32x32 i8 (CDNA family pattern, shape-determined):
//   A: row = lane&31, k-bytes = (lane>>5)*16 within each 32B k-step.
//   B: col = lane&31, same k-bytes -> identical per-lane byte pattern as A,
//      so any internal k-map cancels (dot is k-perm invariant; same argument
//      as the verified 16x16x64 kernel).
//   C/D: col = lane&31, row = (reg&3) + 8*(reg>>2) + 4*(lane>>5)
//        (m74/m101-verified, dtype-independent per m121-m128).
//
// Staging schedule (identical hazard windows to verified R1 schedule):
//   ph1: A-h0(t+1)->buf1   ph2: A-h1(t+1)->buf1   (buf1-A last read prev ph8)
//   ph3: B-h0(t+2)->buf0   ph4: B-h1(t+2)->buf0   (buf0-B last read ph2)
//   ph5: A-h0(t+2)->buf0   ph6: A-h1(t+2)->buf0   (buf0-A last read ph4)
//   ph7: B-h0(t+3)->buf1   ph8: B-h1(t+3)->buf1   (buf1-B last read ph6)
// vmcnt(4) only at ph4 (tile t+1 landed before ph5 reads it) and ph8
// (tile t+2 landed before next-iter ph1). Never vmcnt(0) in the loop.
// ---------------------------------------------------------------------------
#define BM 256
#define BN 256
#define BKB 128  // K-bytes (=128 int8) per K-tile

#define MFMA32 __builtin_amdgcn_mfma_i32_32x32x32_i8

#define BARRIER()                       \
    do {                                \
        __builtin_amdgcn_s_barrier();   \
        asm volatile("" ::: "memory");  \
    } while (0)

#define LGKM0() asm volatile("s_waitcnt lgkmcnt(0)" ::: "memory")
#define VMCNT4() asm volatile("s_waitcnt vmcnt(4)" ::: "memory")

#define STAGE_HALF(GL, LB, ROWOFF, KK)                                        \
    do {                                                                      \
        __builtin_amdgcn_global_load_lds(                                     \
            (const __attribute__((address_space(1))) void*)(                  \
                (GL) + (size_t)(ROWOFF) * K + (KK)),                          \
            (__attribute__((address_space(3))) void*)((LB) + (ROWOFF) * BKB), \
            16, 0, 0);                                                        \
        __builtin_amdgcn_global_load_lds(                                     \
            (const __attribute__((address_space(1))) void*)(                  \
                (GL) + (size_t)((ROWOFF) + 64) * K + (KK)),                   \
            (__attribute__((address_space(3))) void*)(                        \
                (LB) + ((ROWOFF) + 64) * BKB),                                \
            16, 0, 0);                                                        \
    } while (0)

// A fragments MB,MB+1 at k-step pair KP (ks = 2*KP, 2*KP+1). 4x ds_read_b128.
#define LDA_PAIR(RP, MB, C0, C1)                                           \
    do {                                                                   \
        af[0][0] = *(const int4v*)((RP) + ((MB) + 0) * 4096 + (C0));       \
        af[0][1] = *(const int4v*)((RP) + ((MB) + 0) * 4096 + (C1));       \
        af[1][0] = *(const int4v*)((RP) + ((MB) + 1) * 4096 + (C0));       \
        af[1][1] = *(const int4v*)((RP) + ((MB) + 1) * 4096 + (C1));       \
    } while (0)

// B fragments 0,1 at k-step pair KP. 4x ds_read_b128.
#define LDB_PAIR(RP, KP, C0, C1)                                           \
    do {                                                                   \
        bf[0][(KP)*2 + 0] = *(const int4v*)((RP) + 0 * 4096 + (C0));       \
        bf[0][(KP)*2 + 1] = *(const int4v*)((RP) + 0 * 4096 + (C1));       \
        bf[1][(KP)*2 + 0] = *(const int4v*)((RP) + 1 * 4096 + (C0));       \
        bf[1][(KP)*2 + 1] = *(const int4v*)((RP) + 1 * 4096 + (C1));       \
    } while (0)

// One phase's MFMA cluster: M-pair MB x both N-frags x k-step pair KP.
// ks-outer ordering: same-acc chain distance = 4 instructions.
#define QUAD32(MB, KP)                                                        \
    do {                                                                      \
        _Pragma("unroll") for (int kl_ = 0; kl_ < 2; ++kl_) {                 \
            _Pragma("unroll") for (int m_ = 0; m_ < 2; ++m_) {                \
                _Pragma("unroll") for (int n_ = 0; n_ < 2; ++n_) {            \
                    acc[(MB) + m_][n_] = MFMA32(af[m_][kl_],                  \
                                                bf[n_][(KP)*2 + kl_],         \
                                                acc[(MB) + m_][n_], 0, 0, 0); \
                }                                                             \
            }                                                                 \
        }                                                                     \
    } while (0)

__global__ __launch_bounds__(512, 2) void gemm_i8_kernel(
    const signed char* __restrict__ A,
    const signed char* __restrict__ B,
    const float* __restrict__ xs,    // [M] per-token scale
    const float* __restrict__ wsc,   // [N] per-channel weight scale
    const float* __restrict__ bias,  // [N]
    float* __restrict__ C,
    int M, int N, int K) {
    __shared__ __align__(16) signed char lds[2][2][BM * BKB];  // 128 KiB

    const int tid = threadIdx.x;
    const int lane = tid & 63;
    const int wv = tid >> 6;    // 0..7
    const int wrow = wv >> 2;   // 0..1 -> M half (128 rows)
    const int wcol = wv & 3;    // 0..3 -> N quarter (64 cols)
    const int fr32 = lane & 31; // fragment row/col within 32-tile
    const int kb = lane >> 5;   // k-byte half select

    const int bm = blockIdx.y * BM;
    const int bn = blockIdx.x * BN;

    // Per-lane staging source: row = wv*8 + (lane>>3); 16B-chunk pre-XORed
    // with (row&7) so the linear LDS dest ends up swizzled.
    const int srow = wv * 8 + (lane >> 3);
    const int scol = ((lane & 7) ^ ((lane >> 3) & 7)) << 4;
    const signed char* gA = A + (size_t)(bm + srow) * K + scol;
    const signed char* gB = B + (size_t)(bn + srow) * K + scol;

    // Staging LDS wave bases (HW dest = base + lane*16, linear).
    signed char* wA0 = &lds[0][0][0] + wv * 1024;
    signed char* wA1 = &lds[1][0][0] + wv * 1024;
    signed char* wB0 = &lds[0][1][0] + wv * 1024;
    signed char* wB1 = &lds[1][1][0] + wv * 1024;

    // Fragment read bases; reads apply the same XOR (deswizzle).
    // Chunk byte-offset for k-step ks: ((2*ks + kb) ^ (lane&7)) * 16.
    const int rowA = (wrow * 128 + fr32) * BKB;
    const int rowB = (wcol * 64 + fr32) * BKB;
    const int l7 = lane & 7;
    const int c0 = ((0 + kb) ^ l7) << 4;  // ks=0
    const int c1 = ((2 + kb) ^ l7) << 4;  // ks=1
    const int c2 = ((4 + kb) ^ l7) << 4;  // ks=2
    const int c3 = ((6 + kb) ^ l7) << 4;  // ks=3
    const signed char* rA0 = &lds[0][0][0] + rowA;
    const signed char* rA1 = &lds[1][0][0] + rowA;
    const signed char* rB0 = &lds[0][1][0] + rowB;
    const signed char* rB1 = &lds[1][1][0] + rowB;

    int16v acc[4][2];
    #pragma unroll
    for (int m = 0; m < 4; ++m)
        #pragma unroll
        for (int n = 0; n < 2; ++n)
            #pragma unroll
            for (int e = 0; e < 16; ++e) acc[m][n][e] = 0;
    int4v af[2][2];  // 2 M-frags x 2 local k-steps (reloaded each phase)
    int4v bf[2][4];  // 2 N-frags x all 4 k-steps (live across a K-tile)

    // Prologue: tile0 (A+B) -> buf0, tile1 B -> buf1 (12 loads).
    STAGE_HALF(gA, wA0, 0, 0);
    STAGE_HALF(gA, wA0, 128, 0);
    STAGE_HALF(gB, wB0, 0, 0);
    STAGE_HALF(gB, wB0, 128, 0);
    STAGE_HALF(gB, wB1, 0, (size_t)BKB);
    STAGE_HALF(gB, wB1, 128, (size_t)BKB);
    VMCNT4();  // tile0's 8 loads landed; tile1-B (last 4) may be in flight
    BARRIER();

    const int NT = K / BKB;  // 32 K-tiles
    for (int i = 0; i < NT / 2; ++i) {
        const size_t kk1 = (size_t)(2 * i + 1) * BKB;
        int t2 = 2 * i + 2; if (t2 >= NT) t2 -= NT;  // wrap: stage-only, never read
        int t3 = 2 * i + 3; if (t3 >= NT) t3 -= NT;
        const size_t kk2 = (size_t)t2 * BKB;
        const size_t kk3 = (size_t)t3 * BKB;

        // ---- phase 1: M0-1 x N0-1 x ks0-1 (buf0); stage A-h0(t+1)->buf1
        LDB_PAIR(rB0, 0, c0, c1);
        LDA_PAIR(rA0, 0, c0, c1);
        STAGE_HALF(gA, wA1, 0, kk1);
        BARRIER();
        LGKM0();
        __builtin_amdgcn_s_setprio(1);
        QUAD32(0, 0);
        __builtin_amdgcn_s_setprio(0);
        BARRIER();

        // ---- phase 2: M0-1 x ks2-3; stage A-h1(t+1)->buf1
        LDB_PAIR(rB0, 1, c2, c3);
        LDA_PAIR(rA0, 0, c2, c3);
        STAGE_HALF(gA, wA1, 128, kk1);
        BARRIER();
        LGKM0();
        __builtin_amdgcn_s_setprio(1);
        QUAD32(0, 1);
        __builtin_amdgcn_s_setprio(0);
        BARRIER();

        // ---- phase 3: M2-3 x ks0-1; stage B-h0(t+2)->buf0
        LDA_PAIR(rA0, 2, c0, c1);
        STAGE_HALF(gB, wB0, 0, kk2);
        BARRIER();
        LGKM0();
        __builtin_amdgcn_s_setprio(1);
        QUAD32(2, 0);
        __builtin_amdgcn_s_setprio(0);
        BARRIER();

        // ---- phase 4: M2-3 x ks2-3; stage B-h1(t+2)->buf0; counted vmcnt
        LDA_PAIR(rA0, 2, c2, c3);
        STAGE_HALF(gB, wB0, 128, kk2);
        VMCNT4();  // tile t+1 fully landed (its A: ph1/2, B: prev ph7/8)
        BARRIER();
        LGKM0();
        __builtin_amdgcn_s_setprio(1);
        QUAD32(2, 1);
        __builtin_amdgcn_s_setprio(0);
        BARRIER();

        // ---- phase 5: M0-1 x ks0-1 (buf1); stage A-h0(t+2)->buf0
        LDB_PAIR(rB1, 0, c0, c1);
        LDA_PAIR(rA1, 0, c0, c1);
        STAGE_HALF(gA, wA0, 0, kk2);
        BARRIER();
        LGKM0();
        __builtin_amdgcn_s_setprio(1);
        QUAD32(0, 0);
        __builtin_amdgcn_s_setprio(0);
        BARRIER();

        // ---- phase 6: M0-1 x ks2-3; stage A-h1(t+2)->buf0
        LDB_PAIR(rB1, 1, c2, c3);
        LDA_PAIR(rA1, 0, c2, c3);
        STAGE_HALF(gA, wA0, 128, kk2);
        BARRIER();
        LGKM0();
        __builtin_amdgcn_s_setprio(1);
        QUAD32(0, 1);
        __builtin_amdgcn_s_setprio(0);
        BARRIER();

        // ---- phase 7: M2-3 x ks0-1; stage B-h0(t+3)->buf1
        LDA_PAIR(rA1, 2, c0, c1);
        STAGE_HALF(gB, wB1, 0, kk3);
        BARRIER();
        LGKM0();
        __builtin_amdgcn_s_setprio(1);
        QUAD32(2, 0);
        __builtin_amdgcn_s_setprio(0);
        BARRIER();

        // ---- phase 8: M2-3 x ks2-3; stage B-h1(t+3)->buf1; counted vmcnt
        LDA_PAIR(rA1, 2, c2, c3);
        STAGE_HALF(gB, wB1, 128, kk3);
        VMCNT4();  // tile t+2 fully landed before next-iter ph1
        BARRIER();
        LGKM0();
        __builtin_amdgcn_s_setprio(1);
        QUAD32(2, 1);
        __builtin_amdgcn_s_setprio(0);
        BARRIER();
    }

    // Drain outstanding (wrapped) global_load_lds before LDS goes out of scope.
    asm volatile("s_waitcnt vmcnt(0)" ::: "memory");

    // Epilogue. 32x32 C/D: col = lane&31, row = (reg&3) + 8*(reg>>2) + 4*kb.
    const int cb = bn + wcol * 64;
    float wv2[2], bv2[2];
    #pragma unroll
    for (int n = 0; n < 2; ++n) {
        wv2[n] = wsc[cb + n * 32 + fr32];
        bv2[n] = bias[cb + n * 32 + fr32];
    }
    #pragma unroll
    for (int m = 0; m < 4; ++m) {
        #pragma unroll
        for (int r = 0; r < 16; ++r) {
            const int row = bm + wrow * 128 + m * 32 + (r & 3) + 8 * (r >> 2) + 4 * kb;
            const float s = xs[row];
            float* crow = C + (size_t)row * N + cb + fr32;
            crow[0]  = (float)acc[m][0][r] * s * wv2[0] + bv2[0];
            crow[32] = (float)acc[m][1][r] * s * wv2[1] + bv2[1];
        }
    }
}

// ---------------------------------------------------------------------------
extern "C" void kernel_launch(void* const* d_in, const int* in_sizes, int n_in,
                              void* d_out, int out_size, void* d_ws, size_t ws_size,
                              hipStream_t stream) {
    const float* x = (const float*)d_in[0];
    const int* wq32 = (const int*)d_in[1];  // harness passes integers as int32!
    const float* wscale = (const float*)d_in[2];
    const float* bias = (const float*)d_in[3];
    float* out = (float*)d_out;

    const int d_out_dim = in_sizes[2];             // 4096 (weight_scale length)
    const int d_in_dim = in_sizes[1] / d_out_dim;  // 4096
    const int T = in_sizes[0] / d_in_dim;          // 8192 tokens

    // Workspace: [packed weights][x_q][x_scale]
    const size_t wbytes = (size_t)d_out_dim * d_in_dim;
    signed char* w8 = (signed char*)d_ws;
    signed char* xq = (signed char*)d_ws + wbytes;
    float* xscl = (float*)((char*)d_ws + wbytes + (size_t)T * d_in_dim);

    const long n4 = (long)d_out_dim * d_in_dim / 4;
    pack_w_kernel<<<(int)((n4 + 255) / 256), 256, 0, stream>>>(wq32, (int*)w8, n4);

    if (d_in_dim == 4096) {
        quant_kernel<4><<<T, 256, 0, stream>>>(x, xq, xscl, d_in_dim);
    } else {
        quant_kernel<8><<<T, 256, 0, stream>>>(x, xq, xscl, d_in_dim);
    }

    dim3 grid(d_out_dim / BN, T / BM);
    gemm_i8_kernel<<<grid, 512, 0, stream>>>(xq, w8, xscl, wscale, bias, out,
                                             T, d_out_dim, d_in_dim);
}

// Round 4
// 379.779 us; speedup vs baseline: 1.0517x; 1.0517x over previous
//
#include <hip/hip_runtime.h>

typedef __attribute__((ext_vector_type(4))) int int4v;

// ---------------------------------------------------------------------------
// Kernel 0: pack int32 weights (harness passes ALL integer inputs as int32)
// into contiguous int8. w32: [N*K] int32 in [-127,127] -> w8: [N*K] int8.
// ---------------------------------------------------------------------------
__global__ __launch_bounds__(256) void pack_w_kernel(const int* __restrict__ w32,
                                                     int* __restrict__ w8,
                                                     long n4) {
    long i = (long)blockIdx.x * 256 + threadIdx.x;  // one per 4 ints
    if (i >= n4) return;
    int4v v = ((const int4v*)w32)[i];
    w8[i] = (v[0] & 0xFF) | ((v[1] & 0xFF) << 8) |
            ((v[2] & 0xFF) << 16) | ((v[3] & 0xFF) << 24);
}

// ---------------------------------------------------------------------------
// Kernel 1: dynamic per-token symmetric int8 quantization (unchanged).
// ---------------------------------------------------------------------------
template <int NCHUNK>
__global__ __launch_bounds__(256) void quant_kernel(const float* __restrict__ x,
                                                    signed char* __restrict__ xq,
                                                    float* __restrict__ xs,
                                                    int K) {
    const int t = blockIdx.x;
    const int tid = threadIdx.x;
    const float4* row = (const float4*)(x + (size_t)t * K);

    float4 v[NCHUNK];
    float amax = 0.0f;
    #pragma unroll
    for (int i = 0; i < NCHUNK; ++i) {
        float4 f = row[i * 256 + tid];
        v[i] = f;
        amax = fmaxf(amax, fmaxf(fmaxf(fabsf(f.x), fabsf(f.y)),
                                 fmaxf(fabsf(f.z), fabsf(f.w))));
    }
    #pragma unroll
    for (int off = 32; off >= 1; off >>= 1)
        amax = fmaxf(amax, __shfl_xor(amax, off, 64));
    __shared__ float red[4];
    if ((tid & 63) == 0) red[tid >> 6] = amax;
    __syncthreads();
    amax = fmaxf(fmaxf(red[0], red[1]), fmaxf(red[2], red[3]));

    const float scale = fmaxf(amax, 1e-8f) / 127.0f;
    if (tid == 0) xs[t] = scale;
    const float inv = 1.0f / scale;

    int* orow = (int*)(xq + (size_t)t * K);
    #pragma unroll
    for (int i = 0; i < NCHUNK; ++i) {
        float4 f = v[i];
        int q0 = (int)fminf(fmaxf(rintf(f.x * inv), -128.0f), 127.0f);
        int q1 = (int)fminf(fmaxf(rintf(f.y * inv), -128.0f), 127.0f);
        int q2 = (int)fminf(fmaxf(rintf(f.z * inv), -128.0f), 127.0f);
        int q3 = (int)fminf(fmaxf(rintf(f.w * inv), -128.0f), 127.0f);
        orow[i * 256 + tid] =
            (q0 & 0xFF) | ((q1 & 0xFF) << 8) | ((q2 & 0xFF) << 16) | ((q3 & 0xFF) << 24);
    }
}

// ---------------------------------------------------------------------------
// Kernel 2: int8 GEMM, 256x256 8-phase schedule (T2+T3/T4+T5) on
// v_mfma_i32_16x16x64_i8 — the R1 base (132 us, 0 bank conflicts), with the
// phase decomposition rebalanced from (M-half x N-pair), reads 12/4/8/0,
// to (M-half x k-subtile), reads 8/8/4/4:
//   - worst-phase lgkm chain 12 reads (~144cy) -> 8 reads (~96cy) vs 82cy MFMA
//   - each phase's 16 MFMA now hit 16 DISTINCT accumulators (no same-acc
//     back-to-back chains; R1 relied on compiler interleave).
// ds_read addresses are byte-identical to R1 (same sw0/sw1, same row bases);
// staging schedule, vmcnt(4) placement, and barriers are byte-identical to R1.
// Reads only move LATER than R1, so all R1 hazard windows still hold:
//   buf0-B last read ph2 < ph3 stage; buf0-A last read ph4 < ph5 stage;
//   buf1-B last read ph6 < ph7 stage; buf1-A last read ph8 < next ph1 stage.
// vmcnt(4) at ph4: tile t+1 (A: ph1/2, B: prev ph7/8) landed before ph5 reads;
// at ph8: tile t+2 landed before next-iter ph1. Never vmcnt(0) in the loop.
// ---------------------------------------------------------------------------
#define BM 256
#define BN 256
#define BKB 128  // K-bytes (=128 int8) per K-tile

#define MFMA_I8 __builtin_amdgcn_mfma_i32_16x16x64_i8

#define BARRIER()                       \
    do {                                \
        __builtin_amdgcn_s_barrier();   \
        asm volatile("" ::: "memory");  \
    } while (0)

#define LGKM0() asm volatile("s_waitcnt lgkmcnt(0)" ::: "memory")
#define VMCNT4() asm volatile("s_waitcnt vmcnt(4)" ::: "memory")

#define STAGE_HALF(GL, LB, ROWOFF, KK)                                        \
    do {                                                                      \
        __builtin_amdgcn_global_load_lds(                                     \
            (const __attribute__((address_space(1))) void*)(                  \
                (GL) + (size_t)(ROWOFF) * K + (KK)),                          \
            (__attribute__((address_space(3))) void*)((LB) + (ROWOFF) * BKB), \
            16, 0, 0);                                                        \
        __builtin_amdgcn_global_load_lds(                                     \
            (const __attribute__((address_space(1))) void*)(                  \
                (GL) + (size_t)((ROWOFF) + 64) * K + (KK)),                   \
            (__attribute__((address_space(3))) void*)(                        \
                (LB) + ((ROWOFF) + 64) * BKB),                                \
            16, 0, 0);                                                        \
    } while (0)

// A-fragments m..m+3 (rows (MOFF+i)*16), ONE k-subtile (SW = sw0 or sw1).
#define LDA_KS(RP, MOFF, SW)                                               \
    do {                                                                   \
        af[0] = *(const int4v*)((RP) + ((MOFF) + 0) * 2048 + (SW));        \
        af[1] = *(const int4v*)((RP) + ((MOFF) + 1) * 2048 + (SW));        \
        af[2] = *(const int4v*)((RP) + ((MOFF) + 2) * 2048 + (SW));        \
        af[3] = *(const int4v*)((RP) + ((MOFF) + 3) * 2048 + (SW));        \
    } while (0)

// B-fragments 0..3, ONE k-subtile KS (SW matches KS).
#define LDB_KS(RP, KS, SW)                                                 \
    do {                                                                   \
        bf[0][(KS)] = *(const int4v*)((RP) + 0 * 2048 + (SW));             \
        bf[1][(KS)] = *(const int4v*)((RP) + 1 * 2048 + (SW));             \
        bf[2][(KS)] = *(const int4v*)((RP) + 2 * 2048 + (SW));             \
        bf[3][(KS)] = *(const int4v*)((RP) + 3 * 2048 + (SW));             \
    } while (0)

// One phase's MFMA cluster: M-half MB x all 4 N-frags x k-subtile KS.
// 16 MFMA, 16 distinct accumulators — zero intra-cluster dependencies.
#define PH_MFMA(MB, KS)                                                       \
    do {                                                                      \
        _Pragma("unroll") for (int m_ = 0; m_ < 4; ++m_) {                    \
            _Pragma("unroll") for (int n_ = 0; n_ < 4; ++n_) {                \
                acc[(MB) + m_][n_] = MFMA_I8(af[m_], bf[n_][(KS)],            \
                                             acc[(MB) + m_][n_], 0, 0, 0);    \
            }                                                                 \
        }                                                                     \
    } while (0)

__global__ __launch_bounds__(512, 2) void gemm_i8_kernel(
    const signed char* __restrict__ A,
    const signed char* __restrict__ B,
    const float* __restrict__ xs,    // [M] per-token scale
    const float* __restrict__ wsc,   // [N] per-channel weight scale
    const float* __restrict__ bias,  // [N]
    float* __restrict__ C,
    int M, int N, int K) {
    __shared__ __align__(16) signed char lds[2][2][BM * BKB];  // 128 KiB

    const int tid = threadIdx.x;
    const int lane = tid & 63;
    const int wv = tid >> 6;    // 0..7
    const int wrow = wv >> 2;   // 0..1 -> M half (128 rows)
    const int wcol = wv & 3;    // 0..3 -> N quarter (64 cols)
    const int fr = lane & 15;   // fragment row
    const int q = lane >> 4;    // k-quad

    const int bm = blockIdx.y * BM;
    const int bn = blockIdx.x * BN;

    // Per-lane staging source: row = wv*8 + (lane>>3); 16B-chunk pre-XORed
    // with (row&7) so the linear LDS dest ends up swizzled.
    const int srow = wv * 8 + (lane >> 3);
    const int scol = ((lane & 7) ^ ((lane >> 3) & 7)) << 4;
    const signed char* gA = A + (size_t)(bm + srow) * K + scol;
    const signed char* gB = B + (size_t)(bn + srow) * K + scol;

    // Staging LDS wave bases (HW dest = base + lane*16, linear).
    signed char* wA0 = &lds[0][0][0] + wv * 1024;
    signed char* wA1 = &lds[1][0][0] + wv * 1024;
    signed char* wB0 = &lds[0][1][0] + wv * 1024;
    signed char* wB1 = &lds[1][1][0] + wv * 1024;

    // Fragment read bases; reads apply the same XOR (deswizzle).
    const int rowA = (wrow * 128 + fr) * BKB;
    const int rowB = (wcol * 64 + fr) * BKB;
    const int sw0 = ((0 + q) ^ (fr & 7)) << 4;  // k-subtile 0 chunk
    const int sw1 = ((4 + q) ^ (fr & 7)) << 4;  // k-subtile 1 chunk
    const signed char* rA0 = &lds[0][0][0] + rowA;
    const signed char* rA1 = &lds[1][0][0] + rowA;
    const signed char* rB0 = &lds[0][1][0] + rowB;
    const signed char* rB1 = &lds[1][1][0] + rowB;

    int4v acc[8][4];
    const int4v zero = {0, 0, 0, 0};
    #pragma unroll
    for (int m = 0; m < 8; ++m)
        #pragma unroll
        for (int n = 0; n < 4; ++n) acc[m][n] = zero;
    int4v af[4];     // 4 M-frags, one k-subtile (reloaded each phase)
    int4v bf[4][2];  // 4 N-frags x both k-subtiles (live across 4 phases)

    // Prologue: tile0 (A+B) -> buf0, tile1 B -> buf1 (12 loads).
    STAGE_HALF(gA, wA0, 0, 0);
    STAGE_HALF(gA, wA0, 128, 0);
    STAGE_HALF(gB, wB0, 0, 0);
    STAGE_HALF(gB, wB0, 128, 0);
    STAGE_HALF(gB, wB1, 0, (size_t)BKB);
    STAGE_HALF(gB, wB1, 128, (size_t)BKB);
    VMCNT4();  // tile0's 8 loads landed; tile1-B (last 4) may be in flight
    BARRIER();

    const int NT = K / BKB;  // 32 K-tiles
    for (int i = 0; i < NT / 2; ++i) {
        const size_t kk1 = (size_t)(2 * i + 1) * BKB;
        int t2 = 2 * i + 2; if (t2 >= NT) t2 -= NT;  // wrap: stage-only, never read
        int t3 = 2 * i + 3; if (t3 >= NT) t3 -= NT;
        const size_t kk2 = (size_t)t2 * BKB;
        const size_t kk3 = (size_t)t3 * BKB;

        // ---- phase 1: M0-3 x N0-3 x ks0 (buf0); stage A-h0(t+1)->buf1
        LDA_KS(rA0, 0, sw0);
        LDB_KS(rB0, 0, sw0);
        STAGE_HALF(gA, wA1, 0, kk1);
        BARRIER();
        LGKM0();
        __builtin_amdgcn_s_setprio(1);
        PH_MFMA(0, 0);
        __builtin_amdgcn_s_setprio(0);
        BARRIER();

        // ---- phase 2: M0-3 x ks1; stage A-h1(t+1)->buf1
        LDA_KS(rA0, 0, sw1);
        LDB_KS(rB0, 1, sw1);
        STAGE_HALF(gA, wA1, 128, kk1);
        BARRIER();
        LGKM0();
        __builtin_amdgcn_s_setprio(1);
        PH_MFMA(0, 1);
        __builtin_amdgcn_s_setprio(0);
        BARRIER();

        // ---- phase 3: M4-7 x ks0; stage B-h0(t+2)->buf0
        LDA_KS(rA0, 4, sw0);
        STAGE_HALF(gB, wB0, 0, kk2);
        BARRIER();
        LGKM0();
        __builtin_amdgcn_s_setprio(1);
        PH_MFMA(4, 0);
        __builtin_amdgcn_s_setprio(0);
        BARRIER();

        // ---- phase 4: M4-7 x ks1; stage B-h1(t+2)->buf0; counted vmcnt
        LDA_KS(rA0, 4, sw1);
        STAGE_HALF(gB, wB0, 128, kk2);
        VMCNT4();  // tile t+1 fully landed (its A: ph1/2, B: prev ph7/8)
        BARRIER();
        LGKM0();
        __builtin_amdgcn_s_setprio(1);
        PH_MFMA(4, 1);
        __builtin_amdgcn_s_setprio(0);
        BARRIER();

        // ---- phase 5: M0-3 x ks0 (buf1); stage A-h0(t+2)->buf0
        LDA_KS(rA1, 0, sw0);
        LDB_KS(rB1, 0, sw0);
        STAGE_HALF(gA, wA0, 0, kk2);
        BARRIER();
        LGKM0();
        __builtin_amdgcn_s_setprio(1);
        PH_MFMA(0, 0);
        __builtin_amdgcn_s_setprio(0);
        BARRIER();

        // ---- phase 6: M0-3 x ks1; stage A-h1(t+2)->buf0
        LDA_KS(rA1, 0, sw1);
        LDB_KS(rB1, 1, sw1);
        STAGE_HALF(gA, wA0, 128, kk2);
        BARRIER();
        LGKM0();
        __builtin_amdgcn_s_setprio(1);
        PH_MFMA(0, 1);
        __builtin_amdgcn_s_setprio(0);
        BARRIER();

        // ---- phase 7: M4-7 x ks0; stage B-h0(t+3)->buf1
        LDA_KS(rA1, 4, sw0);
        STAGE_HALF(gB, wB1, 0, kk3);
        BARRIER();
        LGKM0();
        __builtin_amdgcn_s_setprio(1);
        PH_MFMA(4, 0);
        __builtin_amdgcn_s_setprio(0);
        BARRIER();

        // ---- phase 8: M4-7 x ks1; stage B-h1(t+3)->buf1; counted vmcnt
        LDA_KS(rA1, 4, sw1);
        STAGE_HALF(gB, wB1, 128, kk3);
        VMCNT4();  // tile t+2 fully landed before next-iter ph1
        BARRIER();
        LGKM0();
        __builtin_amdgcn_s_setprio(1);
        PH_MFMA(4, 1);
        __builtin_amdgcn_s_setprio(0);
        BARRIER();
    }

    // Drain outstanding (wrapped) global_load_lds before LDS goes out of scope.
    asm volatile("s_waitcnt vmcnt(0)" ::: "memory");

    // Epilogue: C/D layout col(N)=lane&15, row(M)=(lane>>4)*4+reg (m89-verified).
    const int cb = bn + wcol * 64;
    float wv4[4], bv4[4];
    #pragma unroll
    for (int n = 0; n < 4; ++n) {
        wv4[n] = wsc[cb + n * 16 + fr];
        bv4[n] = bias[cb + n * 16 + fr];
    }
    #pragma unroll
    for (int m = 0; m < 8; ++m) {
        #pragma unroll
        for (int r = 0; r < 4; ++r) {
            const int row = bm + wrow * 128 + m * 16 + q * 4 + r;
            const float s = xs[row];
            float* crow = C + (size_t)row * N + cb + fr;
            #pragma unroll
            for (int n = 0; n < 4; ++n)
                crow[n * 16] = (float)acc[m][n][r] * s * wv4[n] + bv4[n];
        }
    }
}

// ---------------------------------------------------------------------------
extern "C" void kernel_launch(void* const* d_in, const int* in_sizes, int n_in,
                              void* d_out, int out_size, void* d_ws, size_t ws_size,
                              hipStream_t stream) {
    const float* x = (const float*)d_in[0];
    const int* wq32 = (const int*)d_in[1];  // harness passes integers as int32!
    const float* wscale = (const float*)d_in[2];
    const float* bias = (const float*)d_in[3];
    float* out = (float*)d_out;

    const int d_out_dim = in_sizes[2];             // 4096 (weight_scale length)
    const int d_in_dim = in_sizes[1] / d_out_dim;  // 4096
    const int T = in_sizes[0] / d_in_dim;          // 8192 tokens

    // Workspace: [packed weights][x_q][x_scale]
    const size_t wbytes = (size_t)d_out_dim * d_in_dim;
    signed char* w8 = (signed char*)d_ws;
    signed char* xq = (signed char*)d_ws + wbytes;
    float* xscl = (float*)((char*)d_ws + wbytes + (size_t)T * d_in_dim);

    const long n4 = (long)d_out_dim * d_in_dim / 4;
    pack_w_kernel<<<(int)((n4 + 255) / 256), 256, 0, stream>>>(wq32, (int*)w8, n4);

    if (d_in_dim == 4096) {
        quant_kernel<4><<<T, 256, 0, stream>>>(x, xq, xscl, d_in_dim);
    } else {
        quant_kernel<8><<<T, 256, 0, stream>>>(x, xq, xscl, d_in_dim);
    }

    dim3 grid(d_out_dim / BN, T / BM);
    gemm_i8_kernel<<<grid, 512, 0, stream>>>(xq, w8, xscl, wscale, bias, out,
                                             T, d_out_dim, d_in_dim);
}

// Round 5
// 375.043 us; speedup vs baseline: 1.0650x; 1.0126x over previous
//
#include <hip/hip_runtime.h>

typedef __attribute__((ext_vector_type(4))) int int4v;

// ---------------------------------------------------------------------------
// Kernel 0: pack int32 weights (harness passes ALL integer inputs as int32)
// into contiguous int8. w32: [N*K] int32 in [-127,127] -> w8: [N*K] int8.
// ---------------------------------------------------------------------------
__global__ __launch_bounds__(256) void pack_w_kernel(const int* __restrict__ w32,
                                                     int* __restrict__ w8,
                                                     long n4) {
    long i = (long)blockIdx.x * 256 + threadIdx.x;  // one per 4 ints
    if (i >= n4) return;
    int4v v = ((const int4v*)w32)[i];
    w8[i] = (v[0] & 0xFF) | ((v[1] & 0xFF) << 8) |
            ((v[2] & 0xFF) << 16) | ((v[3] & 0xFF) << 24);
}

// ---------------------------------------------------------------------------
// Kernel 1: dynamic per-token symmetric int8 quantization (unchanged).
// ---------------------------------------------------------------------------
template <int NCHUNK>
__global__ __launch_bounds__(256) void quant_kernel(const float* __restrict__ x,
                                                    signed char* __restrict__ xq,
                                                    float* __restrict__ xs,
                                                    int K) {
    const int t = blockIdx.x;
    const int tid = threadIdx.x;
    const float4* row = (const float4*)(x + (size_t)t * K);

    float4 v[NCHUNK];
    float amax = 0.0f;
    #pragma unroll
    for (int i = 0; i < NCHUNK; ++i) {
        float4 f = row[i * 256 + tid];
        v[i] = f;
        amax = fmaxf(amax, fmaxf(fmaxf(fabsf(f.x), fabsf(f.y)),
                                 fmaxf(fabsf(f.z), fabsf(f.w))));
    }
    #pragma unroll
    for (int off = 32; off >= 1; off >>= 1)
        amax = fmaxf(amax, __shfl_xor(amax, off, 64));
    __shared__ float red[4];
    if ((tid & 63) == 0) red[tid >> 6] = amax;
    __syncthreads();
    amax = fmaxf(fmaxf(red[0], red[1]), fmaxf(red[2], red[3]));

    const float scale = fmaxf(amax, 1e-8f) / 127.0f;
    if (tid == 0) xs[t] = scale;
    const float inv = 1.0f / scale;

    int* orow = (int*)(xq + (size_t)t * K);
    #pragma unroll
    for (int i = 0; i < NCHUNK; ++i) {
        float4 f = v[i];
        int q0 = (int)fminf(fmaxf(rintf(f.x * inv), -128.0f), 127.0f);
        int q1 = (int)fminf(fmaxf(rintf(f.y * inv), -128.0f), 127.0f);
        int q2 = (int)fminf(fmaxf(rintf(f.z * inv), -128.0f), 127.0f);
        int q3 = (int)fminf(fmaxf(rintf(f.w * inv), -128.0f), 127.0f);
        orow[i * 256 + tid] =
            (q0 & 0xFF) | ((q1 & 0xFF) << 8) | ((q2 & 0xFF) << 16) | ((q3 & 0xFF) << 24);
    }
}

// ---------------------------------------------------------------------------
// Kernel 2: int8 GEMM, 256x256 8-phase schedule (T2+T3/T4+T5) on
// v_mfma_i32_16x16x64_i8, now with REGISTER-LEVEL SOFTWARE PIPELINING:
// each phase's ds_reads are issued ONE PHASE EARLY (ping-pong af[2][4]),
// cross the raw s_barrier as outstanding lgkm ops (raw barrier does not
// drain counters), and complete under the previous phase's MFMA cluster.
// R4 measured reads serialized in front of MFMA every phase (~565cy reads
// + ~653cy MFMA = ~1250cy/phase, MfmaUtil 44%); overlap removes the serial
// read window. Explicit LGKM0 removed: reads are plain C, compiler inserts
// precise lgkmcnt(N) before consuming MFMAs.
//
// Sync structure (barriers, stage slots, vmcnt placement) is byte-identical
// to the R4-verified kernel. Prefetch hazard ledger (slot-by-slot):
//   publication: every prefetch source buffer is published (stager vmcnt +
//   barrier) before the slot it issues in. The two slots whose publication
//   IS the VMCNT4+barrier (ph5-regs at ph4, next-ph1-regs at ph8) issue
//   AFTER that barrier, inside the MFMA window.
//   disjointness: every prefetch source is disjoint from every stage target
//   in its own slot and the next slot (A vs B arrays / buf0 vs buf1), so a
//   read slipping past barriers (lgkm-bounded by the consuming MFMA's wait,
//   <= 1 slot) can never see a concurrent staging write.
// Staging schedule (unchanged, R1/R4-verified):
//   ph1: A-h0(t+1)->buf1   ph2: A-h1(t+1)->buf1
//   ph3: B-h0(t+2)->buf0   ph4: B-h1(t+2)->buf0   VMCNT4 @ ph4
//   ph5: A-h0(t+2)->buf0   ph6: A-h1(t+2)->buf0
//   ph7: B-h0(t+3)->buf1   ph8: B-h1(t+3)->buf1   VMCNT4 @ ph8
// ---------------------------------------------------------------------------
#define BM 256
#define BN 256
#define BKB 128  // K-bytes (=128 int8) per K-tile

#define MFMA_I8 __builtin_amdgcn_mfma_i32_16x16x64_i8

#define BARRIER()                       \
    do {                                \
        __builtin_amdgcn_s_barrier();   \
        asm volatile("" ::: "memory");  \
    } while (0)

#define VMCNT4() asm volatile("s_waitcnt vmcnt(4)" ::: "memory")

#define STAGE_HALF(GL, LB, ROWOFF, KK)                                        \
    do {                                                                      \
        __builtin_amdgcn_global_load_lds(                                     \
            (const __attribute__((address_space(1))) void*)(                  \
                (GL) + (size_t)(ROWOFF) * K + (KK)),                          \
            (__attribute__((address_space(3))) void*)((LB) + (ROWOFF) * BKB), \
            16, 0, 0);                                                        \
        __builtin_amdgcn_global_load_lds(                                     \
            (const __attribute__((address_space(1))) void*)(                  \
                (GL) + (size_t)((ROWOFF) + 64) * K + (KK)),                   \
            (__attribute__((address_space(3))) void*)(                        \
                (LB) + ((ROWOFF) + 64) * BKB),                                \
            16, 0, 0);                                                        \
    } while (0)

// A-fragments rows (MOFF+i)*16, ONE k-subtile, into ping-pong buffer AF.
#define LDA_KS(AF, RP, MOFF, SW)                                           \
    do {                                                                   \
        AF[0] = *(const int4v*)((RP) + ((MOFF) + 0) * 2048 + (SW));        \
        AF[1] = *(const int4v*)((RP) + ((MOFF) + 1) * 2048 + (SW));        \
        AF[2] = *(const int4v*)((RP) + ((MOFF) + 2) * 2048 + (SW));        \
        AF[3] = *(const int4v*)((RP) + ((MOFF) + 3) * 2048 + (SW));        \
    } while (0)

// B-fragments 0..3, k-subtile KS (SW matches KS).
#define LDB_KS(KS, RP, SW)                                                 \
    do {                                                                   \
        bf[0][(KS)] = *(const int4v*)((RP) + 0 * 2048 + (SW));             \
        bf[1][(KS)] = *(const int4v*)((RP) + 1 * 2048 + (SW));             \
        bf[2][(KS)] = *(const int4v*)((RP) + 2 * 2048 + (SW));             \
        bf[3][(KS)] = *(const int4v*)((RP) + 3 * 2048 + (SW));             \
    } while (0)

// One phase's MFMA cluster: M-half MB x all 4 N-frags x k-subtile KS,
// operands from ping-pong buffer AF. 16 distinct accumulators.
#define PH_MFMA(MB, KS, AF)                                                   \
    do {                                                                      \
        _Pragma("unroll") for (int m_ = 0; m_ < 4; ++m_) {                    \
            _Pragma("unroll") for (int n_ = 0; n_ < 4; ++n_) {                \
                acc[(MB) + m_][n_] = MFMA_I8(AF[m_], bf[n_][(KS)],            \
                                             acc[(MB) + m_][n_], 0, 0, 0);    \
            }                                                                 \
        }                                                                     \
    } while (0)

__global__ __launch_bounds__(512, 2) void gemm_i8_kernel(
    const signed char* __restrict__ A,
    const signed char* __restrict__ B,
    const float* __restrict__ xs,    // [M] per-token scale
    const float* __restrict__ wsc,   // [N] per-channel weight scale
    const float* __restrict__ bias,  // [N]
    float* __restrict__ C,
    int M, int N, int K) {
    __shared__ __align__(16) signed char lds[2][2][BM * BKB];  // 128 KiB

    const int tid = threadIdx.x;
    const int lane = tid & 63;
    const int wv = tid >> 6;    // 0..7
    const int wrow = wv >> 2;   // 0..1 -> M half (128 rows)
    const int wcol = wv & 3;    // 0..3 -> N quarter (64 cols)
    const int fr = lane & 15;   // fragment row
    const int q = lane >> 4;    // k-quad

    const int bm = blockIdx.y * BM;
    const int bn = blockIdx.x * BN;

    // Per-lane staging source: row = wv*8 + (lane>>3); 16B-chunk pre-XORed
    // with (row&7) so the linear LDS dest ends up swizzled.
    const int srow = wv * 8 + (lane >> 3);
    const int scol = ((lane & 7) ^ ((lane >> 3) & 7)) << 4;
    const signed char* gA = A + (size_t)(bm + srow) * K + scol;
    const signed char* gB = B + (size_t)(bn + srow) * K + scol;

    // Staging LDS wave bases (HW dest = base + lane*16, linear).
    signed char* wA0 = &lds[0][0][0] + wv * 1024;
    signed char* wA1 = &lds[1][0][0] + wv * 1024;
    signed char* wB0 = &lds[0][1][0] + wv * 1024;
    signed char* wB1 = &lds[1][1][0] + wv * 1024;

    // Fragment read bases; reads apply the same XOR (deswizzle).
    const int rowA = (wrow * 128 + fr) * BKB;
    const int rowB = (wcol * 64 + fr) * BKB;
    const int sw0 = ((0 + q) ^ (fr & 7)) << 4;  // k-subtile 0 chunk
    const int sw1 = ((4 + q) ^ (fr & 7)) << 4;  // k-subtile 1 chunk
    const signed char* rA0 = &lds[0][0][0] + rowA;
    const signed char* rA1 = &lds[1][0][0] + rowA;
    const signed char* rB0 = &lds[0][1][0] + rowB;
    const signed char* rB1 = &lds[1][1][0] + rowB;

    int4v acc[8][4];
    const int4v zero = {0, 0, 0, 0};
    #pragma unroll
    for (int m = 0; m < 8; ++m)
        #pragma unroll
        for (int n = 0; n < 4; ++n) acc[m][n] = zero;
    int4v af[2][4];  // ping-pong A fragments (literal indices only)
    int4v bf[4][2];  // 4 N-frags x both k-subtiles

    // Prologue: tile0 (A+B) -> buf0, tile1 B -> buf1 (12 loads).
    STAGE_HALF(gA, wA0, 0, 0);
    STAGE_HALF(gA, wA0, 128, 0);
    STAGE_HALF(gB, wB0, 0, 0);
    STAGE_HALF(gB, wB0, 128, 0);
    STAGE_HALF(gB, wB1, 0, (size_t)BKB);
    STAGE_HALF(gB, wB1, 128, (size_t)BKB);
    VMCNT4();  // tile0's 8 loads landed; tile1-B (last 4) may be in flight
    BARRIER();

    // Pipeline prime: ph1 regs (buf0, ks0).
    LDA_KS(af[0], rA0, 0, sw0);
    LDB_KS(0, rB0, sw0);

    const int NT = K / BKB;  // 32 K-tiles
    for (int i = 0; i < NT / 2; ++i) {
        const size_t kk1 = (size_t)(2 * i + 1) * BKB;
        int t2 = 2 * i + 2; if (t2 >= NT) t2 -= NT;  // wrap: stage-only, never read
        int t3 = 2 * i + 3; if (t3 >= NT) t3 -= NT;
        const size_t kk2 = (size_t)t2 * BKB;
        const size_t kk3 = (size_t)t3 * BKB;

        // ---- phase 1: MFMA M0-3 ks0 (af[0]); prefetch ph2; stage A-h0(t+1)
        LDA_KS(af[1], rA0, 0, sw1);
        LDB_KS(1, rB0, sw1);
        STAGE_HALF(gA, wA1, 0, kk1);
        BARRIER();
        __builtin_amdgcn_s_setprio(1);
        PH_MFMA(0, 0, af[0]);
        __builtin_amdgcn_s_setprio(0);
        BARRIER();

        // ---- phase 2: MFMA M0-3 ks1 (af[1]); prefetch ph3; stage A-h1(t+1)
        LDA_KS(af[0], rA0, 4, sw0);
        STAGE_HALF(gA, wA1, 128, kk1);
        BARRIER();
        __builtin_amdgcn_s_setprio(1);
        PH_MFMA(0, 1, af[1]);
        __builtin_amdgcn_s_setprio(0);
        BARRIER();

        // ---- phase 3: MFMA M4-7 ks0 (af[0]); prefetch ph4; stage B-h0(t+2)
        LDA_KS(af[1], rA0, 4, sw1);
        STAGE_HALF(gB, wB0, 0, kk2);
        BARRIER();
        __builtin_amdgcn_s_setprio(1);
        PH_MFMA(4, 0, af[0]);
        __builtin_amdgcn_s_setprio(0);
        BARRIER();

        // ---- phase 4: MFMA M4-7 ks1 (af[1]); counted vmcnt; prefetch ph5
        //      AFTER the publish barrier (buf1 tile t+1 guaranteed landed).
        STAGE_HALF(gB, wB0, 128, kk2);
        VMCNT4();  // tile t+1 fully landed (its A: ph1/2, B: prev ph7/8)
        BARRIER();
        LDA_KS(af[0], rA1, 0, sw0);
        LDB_KS(0, rB1, sw0);
        __builtin_amdgcn_s_setprio(1);
        PH_MFMA(4, 1, af[1]);
        __builtin_amdgcn_s_setprio(0);
        BARRIER();

        // ---- phase 5: MFMA M0-3 ks0 buf1 (af[0]); prefetch ph6; stage A-h0(t+2)
        LDA_KS(af[1], rA1, 0, sw1);
        LDB_KS(1, rB1, sw1);
        STAGE_HALF(gA, wA0, 0, kk2);
        BARRIER();
        __builtin_amdgcn_s_setprio(1);
        PH_MFMA(0, 0, af[0]);
        __builtin_amdgcn_s_setprio(0);
        BARRIER();

        // ---- phase 6: MFMA M0-3 ks1 (af[1]); prefetch ph7; stage A-h1(t+2)
        LDA_KS(af[0], rA1, 4, sw0);
        STAGE_HALF(gA, wA0, 128, kk2);
        BARRIER();
        __builtin_amdgcn_s_setprio(1);
        PH_MFMA(0, 1, af[1]);
        __builtin_amdgcn_s_setprio(0);
        BARRIER();

        // ---- phase 7: MFMA M4-7 ks0 (af[0]); prefetch ph8; stage B-h0(t+3)
        LDA_KS(af[1], rA1, 4, sw1);
        STAGE_HALF(gB, wB1, 0, kk3);
        BARRIER();
        __builtin_amdgcn_s_setprio(1);
        PH_MFMA(4, 0, af[0]);
        __builtin_amdgcn_s_setprio(0);
        BARRIER();

        // ---- phase 8: MFMA M4-7 ks1 (af[1]); counted vmcnt; prefetch
        //      next-iter ph1 AFTER the publish barrier (buf0 tile t+2 landed).
        STAGE_HALF(gB, wB1, 128, kk3);
        VMCNT4();  // tile t+2 fully landed before next-iter ph1
        BARRIER();
        LDA_KS(af[0], rA0, 0, sw0);
        LDB_KS(0, rB0, sw0);
        __builtin_amdgcn_s_setprio(1);
        PH_MFMA(4, 1, af[1]);
        __builtin_amdgcn_s_setprio(0);
        BARRIER();
    }

    // Drain outstanding (wrapped) global_load_lds before LDS goes out of scope.
    asm volatile("s_waitcnt vmcnt(0)" ::: "memory");

    // Epilogue: C/D layout col(N)=lane&15, row(M)=(lane>>4)*4+reg (m89-verified).
    const int cb = bn + wcol * 64;
    float wv4[4], bv4[4];
    #pragma unroll
    for (int n = 0; n < 4; ++n) {
        wv4[n] = wsc[cb + n * 16 + fr];
        bv4[n] = bias[cb + n * 16 + fr];
    }
    #pragma unroll
    for (int m = 0; m < 8; ++m) {
        #pragma unroll
        for (int r = 0; r < 4; ++r) {
            const int row = bm + wrow * 128 + m * 16 + q * 4 + r;
            const float s = xs[row];
            float* crow = C + (size_t)row * N + cb + fr;
            #pragma unroll
            for (int n = 0; n < 4; ++n)
                crow[n * 16] = (float)acc[m][n][r] * s * wv4[n] + bv4[n];
        }
    }
}

// ---------------------------------------------------------------------------
extern "C" void kernel_launch(void* const* d_in, const int* in_sizes, int n_in,
                              void* d_out, int out_size, void* d_ws, size_t ws_size,
                              hipStream_t stream) {
    const float* x = (const float*)d_in[0];
    const int* wq32 = (const int*)d_in[1];  // harness passes integers as int32!
    const float* wscale = (const float*)d_in[2];
    const float* bias = (const float*)d_in[3];
    float* out = (float*)d_out;

    const int d_out_dim = in_sizes[2];             // 4096 (weight_scale length)
    const int d_in_dim = in_sizes[1] / d_out_dim;  // 4096
    const int T = in_sizes[0] / d_in_dim;          // 8192 tokens

    // Workspace: [packed weights][x_q][x_scale]
    const size_t wbytes = (size_t)d_out_dim * d_in_dim;
    signed char* w8 = (signed char*)d_ws;
    signed char* xq = (signed char*)d_ws + wbytes;
    float* xscl = (float*)((char*)d_ws + wbytes + (size_t)T * d_in_dim);

    const long n4 = (long)d_out_dim * d_in_dim / 4;
    pack_w_kernel<<<(int)((n4 + 255) / 256), 256, 0, stream>>>(wq32, (int*)w8, n4);

    if (d_in_dim == 4096) {
        quant_kernel<4><<<T, 256, 0, stream>>>(x, xq, xscl, d_in_dim);
    } else {
        quant_kernel<8><<<T, 256, 0, stream>>>(x, xq, xscl, d_in_dim);
    }

    dim3 grid(d_out_dim / BN, T / BM);
    gemm_i8_kernel<<<grid, 512, 0, stream>>>(xq, w8, xscl, wscale, bias, out,
                                             T, d_out_dim, d_in_dim);
}

// Round 6
// 371.305 us; speedup vs baseline: 1.0757x; 1.0101x over previous
//
#include <hip/hip_runtime.h>

typedef __attribute__((ext_vector_type(4))) int int4v;

// ---------------------------------------------------------------------------
// Kernel 0: pack int32 weights (harness passes ALL integer inputs as int32)
// into contiguous int8. w32: [N*K] int32 in [-127,127] -> w8: [N*K] int8.
// ---------------------------------------------------------------------------
__global__ __launch_bounds__(256) void pack_w_kernel(const int* __restrict__ w32,
                                                     int* __restrict__ w8,
                                                     long n4) {
    long i = (long)blockIdx.x * 256 + threadIdx.x;  // one per 4 ints
    if (i >= n4) return;
    int4v v = ((const int4v*)w32)[i];
    w8[i] = (v[0] & 0xFF) | ((v[1] & 0xFF) << 8) |
            ((v[2] & 0xFF) << 16) | ((v[3] & 0xFF) << 24);
}

// ---------------------------------------------------------------------------
// Kernel 1: dynamic per-token symmetric int8 quantization (unchanged).
// ---------------------------------------------------------------------------
template <int NCHUNK>
__global__ __launch_bounds__(256) void quant_kernel(const float* __restrict__ x,
                                                    signed char* __restrict__ xq,
                                                    float* __restrict__ xs,
                                                    int K) {
    const int t = blockIdx.x;
    const int tid = threadIdx.x;
    const float4* row = (const float4*)(x + (size_t)t * K);

    float4 v[NCHUNK];
    float amax = 0.0f;
    #pragma unroll
    for (int i = 0; i < NCHUNK; ++i) {
        float4 f = row[i * 256 + tid];
        v[i] = f;
        amax = fmaxf(amax, fmaxf(fmaxf(fabsf(f.x), fabsf(f.y)),
                                 fmaxf(fabsf(f.z), fabsf(f.w))));
    }
    #pragma unroll
    for (int off = 32; off >= 1; off >>= 1)
        amax = fmaxf(amax, __shfl_xor(amax, off, 64));
    __shared__ float red[4];
    if ((tid & 63) == 0) red[tid >> 6] = amax;
    __syncthreads();
    amax = fmaxf(fmaxf(red[0], red[1]), fmaxf(red[2], red[3]));

    const float scale = fmaxf(amax, 1e-8f) / 127.0f;
    if (tid == 0) xs[t] = scale;
    const float inv = 1.0f / scale;

    int* orow = (int*)(xq + (size_t)t * K);
    #pragma unroll
    for (int i = 0; i < NCHUNK; ++i) {
        float4 f = v[i];
        int q0 = (int)fminf(fmaxf(rintf(f.x * inv), -128.0f), 127.0f);
        int q1 = (int)fminf(fmaxf(rintf(f.y * inv), -128.0f), 127.0f);
        int q2 = (int)fminf(fmaxf(rintf(f.z * inv), -128.0f), 127.0f);
        int q3 = (int)fminf(fmaxf(rintf(f.w * inv), -128.0f), 127.0f);
        orow[i * 256 + tid] =
            (q0 & 0xFF) | ((q1 & 0xFF) << 8) | ((q2 & 0xFF) << 16) | ((q3 & 0xFF) << 24);
    }
}

// ---------------------------------------------------------------------------
// Kernel 2: int8 GEMM, 256x256, 8 phases per 2 K-tiles, now with ONE BARRIER
// PER PHASE (16 -> 8 barriers per 2-K-tiles). R1/R4/R5 all measured ~1250
// cy/phase at MfmaUtil 44% across three read schedules -> the serial tax is
// the per-phase barrier PAIR, not read placement. Removing the post-MFMA
// barrier lets waves skew by up to one phase: one wave issues reads+stage
// for phase k+1 while its SIMD partner finishes MFMA-k (the T5 role split).
//
// 1-barrier hazard ledger (max skew = 1 phase, all pairs checked):
//   - S_{k+1} targets vs R_{k+1}/R_k sources: disjoint for all k (stage
//     always hits the opposite buffer, or the other operand's region:
//     ph1/2 stage buf1-A vs reads buf0; ph3/4 stage buf0-B vs reads buf0-A;
//     ph5/6 stage buf0-A vs reads buf1; ph7/8 stage buf1-B vs reads buf1-A).
//   - R_{k+2} (fast wave) vs S_k (slow wave's issued writes): disjoint
//     for all k (same table, shifted).
//   - Publication: read slots identical to R5's verified ledger; ph5-regs
//     and next-ph1-regs still issue AFTER the publishing VMCNT4+BARRIER.
//   - VMCNT4 counts unchanged (stage slots byte-identical): at ph4 the 4
//     newest = B(t+2) -> all of tile t+1 landed; at ph8 -> tile t+2 landed.
// Staging schedule (R1-verified, unchanged):
//   ph1: A-h0(t+1)->buf1   ph2: A-h1(t+1)->buf1
//   ph3: B-h0(t+2)->buf0   ph4: B-h1(t+2)->buf0   VMCNT4 @ ph4
//   ph5: A-h0(t+2)->buf0   ph6: A-h1(t+2)->buf0
//   ph7: B-h0(t+3)->buf1   ph8: B-h1(t+3)->buf1   VMCNT4 @ ph8
// ---------------------------------------------------------------------------
#define BM 256
#define BN 256
#define BKB 128  // K-bytes (=128 int8) per K-tile

#define MFMA_I8 __builtin_amdgcn_mfma_i32_16x16x64_i8

#define BARRIER()                       \
    do {                                \
        __builtin_amdgcn_s_barrier();   \
        asm volatile("" ::: "memory");  \
    } while (0)

#define VMCNT4() asm volatile("s_waitcnt vmcnt(4)" ::: "memory")

#define STAGE_HALF(GL, LB, ROWOFF, KK)                                        \
    do {                                                                      \
        __builtin_amdgcn_global_load_lds(                                     \
            (const __attribute__((address_space(1))) void*)(                  \
                (GL) + (size_t)(ROWOFF) * K + (KK)),                          \
            (__attribute__((address_space(3))) void*)((LB) + (ROWOFF) * BKB), \
            16, 0, 0);                                                        \
        __builtin_amdgcn_global_load_lds(                                     \
            (const __attribute__((address_space(1))) void*)(                  \
                (GL) + (size_t)((ROWOFF) + 64) * K + (KK)),                   \
            (__attribute__((address_space(3))) void*)(                        \
                (LB) + ((ROWOFF) + 64) * BKB),                                \
            16, 0, 0);                                                        \
    } while (0)

// A-fragments rows (MOFF+i)*16, ONE k-subtile, into ping-pong buffer AF.
#define LDA_KS(AF, RP, MOFF, SW)                                           \
    do {                                                                   \
        AF[0] = *(const int4v*)((RP) + ((MOFF) + 0) * 2048 + (SW));        \
        AF[1] = *(const int4v*)((RP) + ((MOFF) + 1) * 2048 + (SW));        \
        AF[2] = *(const int4v*)((RP) + ((MOFF) + 2) * 2048 + (SW));        \
        AF[3] = *(const int4v*)((RP) + ((MOFF) + 3) * 2048 + (SW));        \
    } while (0)

// B-fragments 0..3, k-subtile KS (SW matches KS).
#define LDB_KS(KS, RP, SW)                                                 \
    do {                                                                   \
        bf[0][(KS)] = *(const int4v*)((RP) + 0 * 2048 + (SW));             \
        bf[1][(KS)] = *(const int4v*)((RP) + 1 * 2048 + (SW));             \
        bf[2][(KS)] = *(const int4v*)((RP) + 2 * 2048 + (SW));             \
        bf[3][(KS)] = *(const int4v*)((RP) + 3 * 2048 + (SW));             \
    } while (0)

// One phase's MFMA cluster: M-half MB x all 4 N-frags x k-subtile KS,
// operands from ping-pong buffer AF. 16 distinct accumulators.
#define PH_MFMA(MB, KS, AF)                                                   \
    do {                                                                      \
        _Pragma("unroll") for (int m_ = 0; m_ < 4; ++m_) {                    \
            _Pragma("unroll") for (int n_ = 0; n_ < 4; ++n_) {                \
                acc[(MB) + m_][n_] = MFMA_I8(AF[m_], bf[n_][(KS)],            \
                                             acc[(MB) + m_][n_], 0, 0, 0);    \
            }                                                                 \
        }                                                                     \
    } while (0)

__global__ __launch_bounds__(512, 2) void gemm_i8_kernel(
    const signed char* __restrict__ A,
    const signed char* __restrict__ B,
    const float* __restrict__ xs,    // [M] per-token scale
    const float* __restrict__ wsc,   // [N] per-channel weight scale
    const float* __restrict__ bias,  // [N]
    float* __restrict__ C,
    int M, int N, int K) {
    __shared__ __align__(16) signed char lds[2][2][BM * BKB];  // 128 KiB

    const int tid = threadIdx.x;
    const int lane = tid & 63;
    const int wv = tid >> 6;    // 0..7
    const int wrow = wv >> 2;   // 0..1 -> M half (128 rows)
    const int wcol = wv & 3;    // 0..3 -> N quarter (64 cols)
    const int fr = lane & 15;   // fragment row
    const int q = lane >> 4;    // k-quad

    const int bm = blockIdx.y * BM;
    const int bn = blockIdx.x * BN;

    // Per-lane staging source: row = wv*8 + (lane>>3); 16B-chunk pre-XORed
    // with (row&7) so the linear LDS dest ends up swizzled.
    const int srow = wv * 8 + (lane >> 3);
    const int scol = ((lane & 7) ^ ((lane >> 3) & 7)) << 4;
    const signed char* gA = A + (size_t)(bm + srow) * K + scol;
    const signed char* gB = B + (size_t)(bn + srow) * K + scol;

    // Staging LDS wave bases (HW dest = base + lane*16, linear).
    signed char* wA0 = &lds[0][0][0] + wv * 1024;
    signed char* wA1 = &lds[1][0][0] + wv * 1024;
    signed char* wB0 = &lds[0][1][0] + wv * 1024;
    signed char* wB1 = &lds[1][1][0] + wv * 1024;

    // Fragment read bases; reads apply the same XOR (deswizzle).
    const int rowA = (wrow * 128 + fr) * BKB;
    const int rowB = (wcol * 64 + fr) * BKB;
    const int sw0 = ((0 + q) ^ (fr & 7)) << 4;  // k-subtile 0 chunk
    const int sw1 = ((4 + q) ^ (fr & 7)) << 4;  // k-subtile 1 chunk
    const signed char* rA0 = &lds[0][0][0] + rowA;
    const signed char* rA1 = &lds[1][0][0] + rowA;
    const signed char* rB0 = &lds[0][1][0] + rowB;
    const signed char* rB1 = &lds[1][1][0] + rowB;

    int4v acc[8][4];
    const int4v zero = {0, 0, 0, 0};
    #pragma unroll
    for (int m = 0; m < 8; ++m)
        #pragma unroll
        for (int n = 0; n < 4; ++n) acc[m][n] = zero;
    int4v af[2][4];  // ping-pong A fragments (literal indices only)
    int4v bf[4][2];  // 4 N-frags x both k-subtiles

    // Prologue: tile0 (A+B) -> buf0, tile1 B -> buf1 (12 loads).
    STAGE_HALF(gA, wA0, 0, 0);
    STAGE_HALF(gA, wA0, 128, 0);
    STAGE_HALF(gB, wB0, 0, 0);
    STAGE_HALF(gB, wB0, 128, 0);
    STAGE_HALF(gB, wB1, 0, (size_t)BKB);
    STAGE_HALF(gB, wB1, 128, (size_t)BKB);
    VMCNT4();  // tile0's 8 loads landed; tile1-B (last 4) may be in flight
    BARRIER();

    // Pipeline prime: ph1 regs (buf0, ks0).
    LDA_KS(af[0], rA0, 0, sw0);
    LDB_KS(0, rB0, sw0);

    const int NT = K / BKB;  // 32 K-tiles
    for (int i = 0; i < NT / 2; ++i) {
        const size_t kk1 = (size_t)(2 * i + 1) * BKB;
        int t2 = 2 * i + 2; if (t2 >= NT) t2 -= NT;  // wrap: stage-only, never read
        int t3 = 2 * i + 3; if (t3 >= NT) t3 -= NT;
        const size_t kk2 = (size_t)t2 * BKB;
        const size_t kk3 = (size_t)t3 * BKB;

        // ---- phase 1: prefetch ph2; stage A-h0(t+1); MFMA M0-3 ks0 (af[0])
        LDA_KS(af[1], rA0, 0, sw1);
        LDB_KS(1, rB0, sw1);
        STAGE_HALF(gA, wA1, 0, kk1);
        BARRIER();
        __builtin_amdgcn_s_setprio(1);
        PH_MFMA(0, 0, af[0]);
        __builtin_amdgcn_s_setprio(0);

        // ---- phase 2: prefetch ph3; stage A-h1(t+1); MFMA M0-3 ks1 (af[1])
        LDA_KS(af[0], rA0, 4, sw0);
        STAGE_HALF(gA, wA1, 128, kk1);
        BARRIER();
        __builtin_amdgcn_s_setprio(1);
        PH_MFMA(0, 1, af[1]);
        __builtin_amdgcn_s_setprio(0);

        // ---- phase 3: prefetch ph4; stage B-h0(t+2); MFMA M4-7 ks0 (af[0])
        LDA_KS(af[1], rA0, 4, sw1);
        STAGE_HALF(gB, wB0, 0, kk2);
        BARRIER();
        __builtin_amdgcn_s_setprio(1);
        PH_MFMA(4, 0, af[0]);
        __builtin_amdgcn_s_setprio(0);

        // ---- phase 4: stage B-h1(t+2); counted vmcnt; prefetch ph5 AFTER
        //      the publish barrier (buf1 tile t+1 guaranteed landed).
        STAGE_HALF(gB, wB0, 128, kk2);
        VMCNT4();  // tile t+1 fully landed (its A: ph1/2, B: prev ph7/8)
        BARRIER();
        LDA_KS(af[0], rA1, 0, sw0);
        LDB_KS(0, rB1, sw0);
        __builtin_amdgcn_s_setprio(1);
        PH_MFMA(4, 1, af[1]);
        __builtin_amdgcn_s_setprio(0);

        // ---- phase 5: prefetch ph6; stage A-h0(t+2); MFMA M0-3 ks0 buf1
        LDA_KS(af[1], rA1, 0, sw1);
        LDB_KS(1, rB1, sw1);
        STAGE_HALF(gA, wA0, 0, kk2);
        BARRIER();
        __builtin_amdgcn_s_setprio(1);
        PH_MFMA(0, 0, af[0]);
        __builtin_amdgcn_s_setprio(0);

        // ---- phase 6: prefetch ph7; stage A-h1(t+2); MFMA M0-3 ks1 (af[1])
        LDA_KS(af[0], rA1, 4, sw0);
        STAGE_HALF(gA, wA0, 128, kk2);
        BARRIER();
        __builtin_amdgcn_s_setprio(1);
        PH_MFMA(0, 1, af[1]);
        __builtin_amdgcn_s_setprio(0);

        // ---- phase 7: prefetch ph8; stage B-h0(t+3); MFMA M4-7 ks0 (af[0])
        LDA_KS(af[1], rA1, 4, sw1);
        STAGE_HALF(gB, wB1, 0, kk3);
        BARRIER();
        __builtin_amdgcn_s_setprio(1);
        PH_MFMA(4, 0, af[0]);
        __builtin_amdgcn_s_setprio(0);

        // ---- phase 8: stage B-h1(t+3); counted vmcnt; prefetch next-iter
        //      ph1 AFTER the publish barrier (buf0 tile t+2 landed).
        STAGE_HALF(gB, wB1, 128, kk3);
        VMCNT4();  // tile t+2 fully landed before next-iter ph1
        BARRIER();
        LDA_KS(af[0], rA0, 0, sw0);
        LDB_KS(0, rB0, sw0);
        __builtin_amdgcn_s_setprio(1);
        PH_MFMA(4, 1, af[1]);
        __builtin_amdgcn_s_setprio(0);
    }

    // Drain outstanding (wrapped) global_load_lds before LDS goes out of scope.
    asm volatile("s_waitcnt vmcnt(0)" ::: "memory");

    // Epilogue: C/D layout col(N)=lane&15, row(M)=(lane>>4)*4+reg (m89-verified).
    const int cb = bn + wcol * 64;
    float wv4[4], bv4[4];
    #pragma unroll
    for (int n = 0; n < 4; ++n) {
        wv4[n] = wsc[cb + n * 16 + fr];
        bv4[n] = bias[cb + n * 16 + fr];
    }
    #pragma unroll
    for (int m = 0; m < 8; ++m) {
        #pragma unroll
        for (int r = 0; r < 4; ++r) {
            const int row = bm + wrow * 128 + m * 16 + q * 4 + r;
            const float s = xs[row];
            float* crow = C + (size_t)row * N + cb + fr;
            #pragma unroll
            for (int n = 0; n < 4; ++n)
                crow[n * 16] = (float)acc[m][n][r] * s * wv4[n] + bv4[n];
        }
    }
}

// ---------------------------------------------------------------------------
extern "C" void kernel_launch(void* const* d_in, const int* in_sizes, int n_in,
                              void* d_out, int out_size, void* d_ws, size_t ws_size,
                              hipStream_t stream) {
    const float* x = (const float*)d_in[0];
    const int* wq32 = (const int*)d_in[1];  // harness passes integers as int32!
    const float* wscale = (const float*)d_in[2];
    const float* bias = (const float*)d_in[3];
    float* out = (float*)d_out;

    const int d_out_dim = in_sizes[2];             // 4096 (weight_scale length)
    const int d_in_dim = in_sizes[1] / d_out_dim;  // 4096
    const int T = in_sizes[0] / d_in_dim;          // 8192 tokens

    // Workspace: [packed weights][x_q][x_scale]
    const size_t wbytes = (size_t)d_out_dim * d_in_dim;
    signed char* w8 = (signed char*)d_ws;
    signed char* xq = (signed char*)d_ws + wbytes;
    float* xscl = (float*)((char*)d_ws + wbytes + (size_t)T * d_in_dim);

    const long n4 = (long)d_out_dim * d_in_dim / 4;
    pack_w_kernel<<<(int)((n4 + 255) / 256), 256, 0, stream>>>(wq32, (int*)w8, n4);

    if (d_in_dim == 4096) {
        quant_kernel<4><<<T, 256, 0, stream>>>(x, xq, xscl, d_in_dim);
    } else {
        quant_kernel<8><<<T, 256, 0, stream>>>(x, xq, xscl, d_in_dim);
    }

    dim3 grid(d_out_dim / BN, T / BM);
    gemm_i8_kernel<<<grid, 512, 0, stream>>>(xq, w8, xscl, wscale, bias, out,
                                             T, d_out_dim, d_in_dim);
}